// Round 14
// baseline (81.054 us; speedup 1.0000x reference)
//
#include <hip/hip_runtime.h>
#include <math.h>

#define DF 512
#define GP 513          // padded Gt row stride (floats)
#define CAP 4096        // bucket slots per element (λ≈2810, 24σ margin)
#define YLP 260         // padded k-stride for YlT/DlT

__device__ __constant__ int c_lidx[16] = {0,1,1,1,2,2,2,2,2,3,3,3,3,3,3,3};

__device__ inline void sh_eval(float x, float y, float z, float* o)
{
    float x2 = x*x, y2 = y*y, z2 = z*z;
    o[0]  = 0.28209479177387814f;
    o[1]  = 0.4886025119029199f*y;
    o[2]  = 0.4886025119029199f*z;
    o[3]  = 0.4886025119029199f*x;
    o[4]  = 1.0925484305920792f*x*y;
    o[5]  = 1.0925484305920792f*y*z;
    o[6]  = 0.31539156525252005f*(3.0f*z2 - 1.0f);
    o[7]  = 1.0925484305920792f*x*z;
    o[8]  = 0.5462742152960396f*(x2 - y2);
    o[9]  = 0.5900435899266435f*y*(3.0f*x2 - y2);
    o[10] = 2.890611442640554f*x*y*z;
    o[11] = 0.4570457994644658f*y*(5.0f*z2 - 1.0f);
    o[12] = 0.3731763325901154f*z*(5.0f*z2 - 3.0f);
    o[13] = 0.4570457994644658f*x*(5.0f*z2 - 1.0f);
    o[14] = 1.445305721320277f*z*(x2 - y2);
    o[15] = 0.5900435899266435f*x*(x2 - 3.0f*y2);
}

__device__ inline void edge_dir(const float* __restrict__ pos, int s, int d,
                                float cx, float cy, float cz,
                                float& x, float& y, float& z)
{
    float ex = pos[d*3+0] - pos[s*3+0];
    float ey = pos[d*3+1] - pos[s*3+1];
    float ez = pos[d*3+2] - pos[s*3+2];
    ex -= rintf(ex/cx)*cx;
    ey -= rintf(ey/cy)*cy;
    ez -= rintf(ez/cz)*cz;
    float len = fmaxf(sqrtf(ex*ex + ey*ey + ez*ez), 1e-8f);
    x = ex/len; y = ey/len; z = ez/len;
}

// us[c*16+m] = sum_d tw1[l(m)][c][d] * v[d*16+m]   (256 threads, 2 outputs each)
__device__ inline void compute_u1(const float* __restrict__ tw1,
                                  const float* __restrict__ v,
                                  float* __restrict__ us, int t)
{
    #pragma unroll
    for (int rep = 0; rep < 2; rep++) {
        int f = t + rep*256;
        int c = f >> 4, m = f & 15, l = c_lidx[m];
        float u = 0.0f;
        #pragma unroll
        for (int d = 0; d < 32; d++) u = fmaf(tw1[l*1024 + c*32 + d], v[d*16 + m], u);
        us[f] = u;
    }
}

// L1: [0,64) vtmp=lw1@ow; [64,128) wv0=lw0@ow; [128,128+NE) tfe; rest: init
// init covers: yacc zeros | bucket=-1 | cursor[a]=a*CAP | out=0 | ncount=0
__global__ __launch_bounds__(512) void k_L1(const float* __restrict__ lw1,
                                            const float* __restrict__ lw0,
                                            const float* __restrict__ ow,
                                            const float* __restrict__ emb,
                                            const float* __restrict__ tw0,
                                            float* __restrict__ vtmp,
                                            float* __restrict__ wv0,
                                            float* __restrict__ tfe,
                                            uint4* __restrict__ yacc4, int nyacc4,
                                            int4* __restrict__ bucket4, int nbucket4,
                                            int* __restrict__ cursor,
                                            int* __restrict__ ncount,
                                            float* __restrict__ out, int NE)
{
    int b = blockIdx.x, t = threadIdx.x;
    if (b < 128) {
        const float* w = (b < 64) ? lw1 : lw0;
        float* v = (b < 64) ? vtmp : wv0;
        int bb = b & 63;
        int r = bb*8 + (t >> 6);
        int lane = t & 63;
        const float* row = w + (size_t)r * DF;
        float s = 0.0f;
        #pragma unroll
        for (int j = 0; j < 8; j++) s += row[lane + j*64] * ow[lane + j*64];
        #pragma unroll
        for (int off = 32; off > 0; off >>= 1) s += __shfl_xor(s, off, 64);
        if (lane == 0) v[r] = s;
    } else if (b < 128 + NE) {
        __shared__ float nf[DF];
        __shared__ float w[4*32*32];
        int a = b - 128;
        nf[t] = emb[(size_t)a*DF + t];
        for (int i = t; i < 4096; i += 512) w[i] = tw0[i];
        __syncthreads();
        int d = t >> 4, m = t & 15;
        int l = c_lidx[m];
        const float* wl = &w[l*1024 + d];
        float acc = 0.0f;
        #pragma unroll
        for (int c = 0; c < 32; c++) acc += nf[c*16 + m] * wl[c*32];
        tfe[(size_t)a*DF + t] = acc;
    } else {
        long i = (long)(b - 128 - NE)*512 + t;
        if (i < nyacc4) { yacc4[i] = make_uint4(0,0,0,0); return; }
        long j = i - nyacc4;
        if (j < nbucket4) { bucket4[j] = make_int4(-1,-1,-1,-1); return; }
        long k = j - nbucket4;
        if (k < 89) cursor[k] = (int)k * CAP;
        else if (k == 89) out[0] = 0.0f;
        else if (k < 180) ncount[k - 90] = 0;
    }
}

// L2: [0,EB) yacc atomics; [EB,2EB) bucket fill; [2EB,2EB+NHB) node hist;
//     [.., +NE) T (f32); [.., +NE) helem; last: bias
__global__ __launch_bounds__(256) void k_L2(const float* __restrict__ pos,
                                            const int* __restrict__ src,
                                            const int* __restrict__ dst,
                                            const int* __restrict__ an,
                                            const float* __restrict__ cell,
                                            const float* __restrict__ vtmp,
                                            const float* __restrict__ wv0,
                                            const float* __restrict__ tw1,
                                            const float* __restrict__ lw0,
                                            const float* __restrict__ lb0,
                                            const float* __restrict__ lb1,
                                            const float* __restrict__ ow,
                                            const float* __restrict__ ob,
                                            const float* __restrict__ emb,
                                            const float* __restrict__ tfe,
                                            float* __restrict__ yacc,
                                            int* __restrict__ cursor,
                                            int* __restrict__ bucket,
                                            int* __restrict__ ncount,
                                            float* __restrict__ T,
                                            float* __restrict__ t1,
                                            float* __restrict__ hf,
                                            float* __restrict__ embdot,
                                            float* __restrict__ out,
                                            int E, int N, int NE, int EB, int NHB)
{
    __shared__ __align__(16) float smem[512 + 512 + 16*GP];   // 36.9 KB max role
    int b = blockIdx.x, t = threadIdx.x;
    if (b < EB) {
        // ---- SH + yacc atomics ----
        float* Yl = smem;                       // [256][17]
        int* sAl = (int*)(smem + 256*17);
        int e = b*256 + t;
        float cx = cell[0], cy = cell[4], cz = cell[8];
        if (e < E) {
            int s = src[e], d = dst[e];
            float x, y, z;
            edge_dir(pos, s, d, cx, cy, cz, x, y, z);
            float o[16];
            sh_eval(x, y, z, o);
            #pragma unroll
            for (int j = 0; j < 16; j++) Yl[t*17 + j] = o[j];
            sAl[t] = s;
        }
        __syncthreads();
        int lastvalid = min(256, E - b*256);
        #pragma unroll
        for (int j = 0; j < 16; j++) {
            int idx = j*256 + t;
            int el = idx >> 4, m = idx & 15;
            if (el < lastvalid)
                atomicAdd(&yacc[(size_t)sAl[el]*16 + m], Yl[el*17 + m]);
        }
    } else if (b < 2*EB) {
        // ---- bucket fill: slot = cursor[a]-block-batched + local rank ----
        int* hist = (int*)smem;
        int* base = (int*)smem + 89;
        int e = (b - EB)*256 + t;
        if (t < 89) hist[t] = 0;
        __syncthreads();
        int a = -1, rank = 0;
        int valid = (e < E);
        if (valid) {
            a = an[src[e]];
            rank = atomicAdd(&hist[a], 1);
        }
        __syncthreads();
        if (t < 89 && hist[t] > 0) base[t] = atomicAdd(&cursor[t], hist[t]);
        __syncthreads();
        if (valid) {
            int slot = base[a] + rank;
            if (slot < (a + 1) * CAP) bucket[slot] = e;
        }
    } else if (b < 2*EB + NHB) {
        // ---- node-element histogram ----
        int* h = (int*)smem;
        int n = (b - 2*EB)*256 + t;
        if (t < 89) h[t] = 0;
        __syncthreads();
        if (n < N) atomicAdd(&h[an[n]], 1);
        __syncthreads();
        if (t < 89 && h[t] > 0) atomicAdd(&ncount[t], h[t]);
    } else if (b < 2*EB + NHB + NE) {
        // ---- T-block (f32): local u1, local Gt, emit T + t1 ----
        int a = b - 2*EB - NHB;
        float* us = smem;
        float* tf = smem + 512;
        float* g  = smem + 1024;                // [16][GP]
        compute_u1(tw1, vtmp, us, t);
        tf[t]       = tfe[(size_t)a*DF + t];
        tf[t + 256] = tfe[(size_t)a*DF + t + 256];
        __syncthreads();
        for (int i = t; i < 16*DF; i += 256) {
            int k = i >> 4, m = i & 15;
            float s = 0.0f;
            #pragma unroll
            for (int c = 0; c < 32; c++)
                s = fmaf(lw0[(size_t)k*DF + c*16 + m], us[c*16 + m], s);
            g[m*GP + k] = s;
        }
        __syncthreads();
        int mm = t >> 4, m = t & 15;
        float s = 0.0f;
        #pragma unroll
        for (int d = 0; d < 32; d++)
            s = fmaf(tf[d*16 + mm], g[m*GP + d*16 + mm], s);
        T[(size_t)a*256 + mm*16 + m] = s;
        if (t < 16) {
            float s1 = 0.0f;
            #pragma unroll
            for (int d = 0; d < 32; d++) s1 = fmaf(tf[d*16 + t], wv0[d*16 + t], s1);
            t1[(size_t)a*16 + t] = s1;
        }
    } else if (b < 2*EB + NHB + 2*NE) {
        // ---- helem: local u1; hf=(emb+lb0).u1 per m; embdot = emb.ow ----
        int a = b - 2*EB - NHB - NE;
        float* us = smem;
        float* r2 = smem + 512;
        float* r1 = smem + 1024;
        compute_u1(tw1, vtmp, us, t);
        float e0 = emb[(size_t)a*DF + t];
        float e1 = emb[(size_t)a*DF + t + 256];
        r1[t] = e0*ow[t] + e1*ow[t+256];
        __syncthreads();
        r2[t]       = (e0 + lb0[t])     * us[t];
        r2[t + 256] = (e1 + lb0[t+256]) * us[t+256];
        __syncthreads();
        for (int s = 128; s > 0; s >>= 1) {
            if (t < s) r1[t] += r1[t + s];
            __syncthreads();
        }
        if (t < 16) {
            float s = 0.0f;
            #pragma unroll
            for (int c = 0; c < 32; c++) s += r2[c*16 + t];
            hf[(size_t)a*16 + t] = s;
        }
        if (t == 0) embdot[a] = r1[0];
    } else {
        // ---- constant bias energy: out += N*((lb0+lb1).ow + ob) ----
        float* red = smem;
        red[t] = (lb0[t] + lb1[t])*ow[t] + (lb0[t+256] + lb1[t+256])*ow[t+256];
        __syncthreads();
        for (int s = 128; s > 0; s >>= 1) {
            if (t < s) red[t] += red[t + s];
            __syncthreads();
        }
        if (t == 0) atomicAdd(out, (float)N * (red[0] + ob[0]));
    }
}

// L3: [0, NE*16) energy blocks (one element per block, 256 bucket slots);
//     [NE*16] embdot-sum.
__global__ __launch_bounds__(256) void k_L3(const float* __restrict__ pos,
                                            const int* __restrict__ src,
                                            const int* __restrict__ dst,
                                            const float* __restrict__ cell,
                                            const int* __restrict__ bucket,
                                            const float* __restrict__ yacc,
                                            const float* __restrict__ T,
                                            const float* __restrict__ t1,
                                            const float* __restrict__ hf,
                                            const float* __restrict__ embdot,
                                            const int* __restrict__ ncount,
                                            float* __restrict__ out, int NE)
{
    int b = blockIdx.x, t = threadIdx.x;
    if (b < NE * 16) {
        __shared__ __align__(16) float YlT[16 * YLP];
        __shared__ __align__(16) float DlT[16 * YLP];
        __shared__ float Taa[256];
        __shared__ float tqs[16];
        __shared__ float wred[4];
        int a = b >> 4;
        int eid = bucket[b*256 + t];
        Taa[t] = T[(size_t)a*256 + t];
        if (t < 16) tqs[t] = t1[(size_t)a*16 + t] + hf[(size_t)a*16 + t];
        int any = __syncthreads_or(eid >= 0 ? 1 : 0);
        if (!any) return;
        float o[16], Dv[16];
        if (eid >= 0) {
            int sn = src[eid], d = dst[eid];
            float x, y, z;
            edge_dir(pos, sn, d, cell[0], cell[4], cell[8], x, y, z);
            sh_eval(x, y, z, o);
            const float4* dp = (const float4*)(yacc + (size_t)d*16);
            float4 D0 = dp[0], D1 = dp[1], D2 = dp[2], D3 = dp[3];
            Dv[0]=D0.x; Dv[1]=D0.y; Dv[2]=D0.z; Dv[3]=D0.w;
            Dv[4]=D1.x; Dv[5]=D1.y; Dv[6]=D1.z; Dv[7]=D1.w;
            Dv[8]=D2.x; Dv[9]=D2.y; Dv[10]=D2.z; Dv[11]=D2.w;
            Dv[12]=D3.x; Dv[13]=D3.y; Dv[14]=D3.z; Dv[15]=D3.w;
        } else {
            #pragma unroll
            for (int j = 0; j < 16; j++) { o[j] = 0.0f; Dv[j] = 0.0f; }
        }
        float se = 0.0f;
        #pragma unroll
        for (int mm = 0; mm < 16; mm++) {
            YlT[mm*YLP + t] = o[mm];
            DlT[mm*YLP + t] = Dv[mm];
            se = fmaf(o[mm], tqs[mm], se);
        }
        __syncthreads();
        int mm = t >> 4, m = t & 15;
        float w = 0.0f;
        #pragma unroll 8
        for (int k = 0; k < 256; k += 4) {
            float4 yv = *(const float4*)&YlT[mm*YLP + k];
            float4 dv = *(const float4*)&DlT[m*YLP + k];
            w += yv.x*dv.x + yv.y*dv.y + yv.z*dv.z + yv.w*dv.w;
        }
        float s = se + w * Taa[t];
        #pragma unroll
        for (int off = 32; off > 0; off >>= 1) s += __shfl_xor(s, off, 64);
        int lane = t & 63, wv = t >> 6;
        if (lane == 0) wred[wv] = s;
        __syncthreads();
        if (t == 0) atomicAdd(out, wred[0] + wred[1] + wred[2] + wred[3]);
    } else {
        // embdot-sum: out += sum_a embdot[a]*ncount[a]
        __shared__ float red[256];
        float v = 0.0f;
        if (t < 89) v = embdot[t] * (float)ncount[t];
        red[t] = v;
        __syncthreads();
        for (int s = 128; s > 0; s >>= 1) {
            if (t < s) red[t] += red[t + s];
            __syncthreads();
        }
        if (t == 0) atomicAdd(out, red[0]);
    }
}

extern "C" void kernel_launch(void* const* d_in, const int* in_sizes, int n_in,
                              void* d_out, int out_size, void* d_ws, size_t ws_size,
                              hipStream_t stream)
{
    const float* pos  = (const float*)d_in[0];
    const float* cell = (const float*)d_in[1];
    const int*   an   = (const int*)d_in[2];
    const int*   ei   = (const int*)d_in[3];
    const float* emb  = (const float*)d_in[4];
    const float* tw0  = (const float*)d_in[5];
    const float* lw0  = (const float*)d_in[6];
    const float* lb0  = (const float*)d_in[7];
    const float* tw1  = (const float*)d_in[8];
    const float* lw1  = (const float*)d_in[9];
    const float* lb1  = (const float*)d_in[10];
    const float* ow   = (const float*)d_in[11];
    const float* ob   = (const float*)d_in[12];
    int N  = in_sizes[0] / 3;
    int E  = in_sizes[3] / 2;
    int NE = in_sizes[4] / DF;   // 89 elements
    const int* src = ei;
    const int* dst = ei + E;

    char* ws = (char*)d_ws;
    size_t off = 0;
    auto alloc = [&](size_t bytes) { void* p = ws + off; off += (bytes + 255) / 256 * 256; return p; };

    float* tfe    = (float*)alloc((size_t)NE * DF * 4);
    float* vtmp   = (float*)alloc(DF * 4);
    float* wv0    = (float*)alloc(DF * 4);
    float* T      = (float*)alloc((size_t)NE * 256 * 4);
    float* t1     = (float*)alloc((size_t)NE * 16 * 4);
    float* hf     = (float*)alloc((size_t)NE * 16 * 4);
    float* embdot = (float*)alloc((size_t)NE * 4);
    float* yacc   = (float*)alloc((size_t)N * 16 * 4);
    int*   bucket = (int*)alloc((size_t)NE * CAP * 4);
    int*   cursor = (int*)alloc(96 * 4);
    int*   ncount = (int*)alloc(96 * 4);

    float* out = (float*)d_out;

    int nyacc4   = N * 4;               // uint4 count for yacc
    int nbucket4 = NE * CAP / 4;        // int4 count for bucket
    long initN   = (long)nyacc4 + nbucket4 + 180;
    int ZB = (int)((initN + 511) / 512);
    k_L1<<<128 + NE + ZB, 512, 0, stream>>>(
        lw1, lw0, ow, emb, tw0, vtmp, wv0, tfe,
        (uint4*)yacc, nyacc4, (int4*)bucket, nbucket4, cursor, ncount, out, NE);

    int EB  = (E + 255) / 256;
    int NHB = (N + 255) / 256;
    k_L2<<<2*EB + NHB + 2*NE + 1, 256, 0, stream>>>(
        pos, src, dst, an, cell, vtmp, wv0, tw1, lw0, lb0, lb1, ow, ob, emb, tfe,
        yacc, cursor, bucket, ncount, T, t1, hf, embdot, out, E, N, NE, EB, NHB);

    k_L3<<<NE*16 + 1, 256, 0, stream>>>(
        pos, src, dst, cell, bucket, yacc, T, t1, hf, embdot, ncount, out, NE);
}

// Round 15
// 62.075 us; speedup vs baseline: 1.3057x; 1.3057x over previous
//
#include <hip/hip_runtime.h>
#include <math.h>

#define DF 512
#define NEMAX 89
#define TPAD 264   // ushorts per padded T row in k_energy LDS
#define T1PAD 17

typedef __attribute__((ext_vector_type(8))) unsigned short ushort8;

__device__ __constant__ int c_lidx[16] = {0,1,1,1,2,2,2,2,2,3,3,3,3,3,3,3};

__device__ inline float bf2f(unsigned short s) {
    union { unsigned int u; float f; } x;
    x.u = ((unsigned int)s) << 16;
    return x.f;
}
__device__ inline unsigned short f2bf(float f) {
    union { float f; unsigned int u; } x; x.f = f;
    unsigned int r = x.u + 0x7fffu + ((x.u >> 16) & 1u);
    return (unsigned short)(r >> 16);
}

__device__ inline void sh_eval(float x, float y, float z, float* o)
{
    float x2 = x*x, y2 = y*y, z2 = z*z;
    o[0]  = 0.28209479177387814f;
    o[1]  = 0.4886025119029199f*y;
    o[2]  = 0.4886025119029199f*z;
    o[3]  = 0.4886025119029199f*x;
    o[4]  = 1.0925484305920792f*x*y;
    o[5]  = 1.0925484305920792f*y*z;
    o[6]  = 0.31539156525252005f*(3.0f*z2 - 1.0f);
    o[7]  = 1.0925484305920792f*x*z;
    o[8]  = 0.5462742152960396f*(x2 - y2);
    o[9]  = 0.5900435899266435f*y*(3.0f*x2 - y2);
    o[10] = 2.890611442640554f*x*y*z;
    o[11] = 0.4570457994644658f*y*(5.0f*z2 - 1.0f);
    o[12] = 0.3731763325901154f*z*(5.0f*z2 - 3.0f);
    o[13] = 0.4570457994644658f*x*(5.0f*z2 - 1.0f);
    o[14] = 1.445305721320277f*z*(x2 - y2);
    o[15] = 0.5900435899266435f*x*(x2 - 3.0f*y2);
}

__device__ inline void edge_dir(const float* __restrict__ pos, int s, int d,
                                float cx, float cy, float cz,
                                float& x, float& y, float& z)
{
    float ex = pos[d*3+0] - pos[s*3+0];
    float ey = pos[d*3+1] - pos[s*3+1];
    float ez = pos[d*3+2] - pos[s*3+2];
    ex -= rintf(ex/cx)*cx;
    ey -= rintf(ey/cy)*cy;
    ez -= rintf(ez/cz)*cz;
    float len = fmaxf(sqrtf(ex*ex + ey*ey + ez*ez), 1e-8f);
    x = ex/len; y = ey/len; z = ez/len;
}

// us[c*16+m] = sum_d tw1[l(m)][c][d] * v[d*16+m]   (256 threads, 2 outputs each)
__device__ inline void compute_u1(const float* __restrict__ tw1,
                                  const float* __restrict__ v,
                                  float* __restrict__ us, int t)
{
    #pragma unroll
    for (int rep = 0; rep < 2; rep++) {
        int f = t + rep*256;
        int c = f >> 4, m = f & 15, l = c_lidx[m];
        float u = 0.0f;
        #pragma unroll
        for (int d = 0; d < 32; d++) u = fmaf(tw1[l*1024 + c*32 + d], v[d*16 + m], u);
        us[f] = u;
    }
}

// K1: [0,64) vtmp=lw1@ow; [64,128) wv0=lw0@ow; [128,128+NE) tfe; rest: zero yacc + out
__global__ __launch_bounds__(512) void k_setup(const float* __restrict__ lw1,
                                               const float* __restrict__ lw0,
                                               const float* __restrict__ ow,
                                               const float* __restrict__ emb,
                                               const float* __restrict__ tw0,
                                               float* __restrict__ vtmp,
                                               float* __restrict__ wv0,
                                               float* __restrict__ tfe,
                                               uint4* __restrict__ yacc4, int nyacc4,
                                               float* __restrict__ out, int NE)
{
    int b = blockIdx.x, t = threadIdx.x;
    if (b < 128) {
        const float* w = (b < 64) ? lw1 : lw0;
        float* v = (b < 64) ? vtmp : wv0;
        int bb = b & 63;
        int r = bb*8 + (t >> 6);
        int lane = t & 63;
        const float* row = w + (size_t)r * DF;
        float s = 0.0f;
        #pragma unroll
        for (int j = 0; j < 8; j++) s += row[lane + j*64] * ow[lane + j*64];
        #pragma unroll
        for (int off = 32; off > 0; off >>= 1) s += __shfl_xor(s, off, 64);
        if (lane == 0) v[r] = s;
    } else if (b < 128 + NE) {
        __shared__ float nf[DF];
        __shared__ float w[4*32*32];
        int a = b - 128;
        nf[t] = emb[(size_t)a*DF + t];
        for (int i = t; i < 4096; i += 512) w[i] = tw0[i];
        __syncthreads();
        int d = t >> 4, m = t & 15;
        int l = c_lidx[m];
        const float* wl = &w[l*1024 + d];
        float acc = 0.0f;
        #pragma unroll
        for (int c = 0; c < 32; c++) acc += nf[c*16 + m] * wl[c*32];
        tfe[(size_t)a*DF + t] = acc;
    } else {
        int i = (b - 128 - NE)*512 + t;
        if (i < nyacc4) yacc4[i] = make_uint4(0,0,0,0);
        if (i == 0) out[0] = 0.0f;
    }
}

// K2 "mid" (18.4 KB LDS, all roles): [0,EB) sh+yacc atomics; [EB,EB+NE) T-direct;
// [EB+NE,EB+2NE) helem; [EB+2NE] bias
__global__ __launch_bounds__(256) void k_mid(const float* __restrict__ pos,
                                             const int* __restrict__ src,
                                             const int* __restrict__ dst,
                                             const float* __restrict__ cell,
                                             const float* __restrict__ vtmp,
                                             const float* __restrict__ wv0,
                                             const float* __restrict__ tw1,
                                             const float* __restrict__ lw0,
                                             const float* __restrict__ lb0,
                                             const float* __restrict__ lb1,
                                             const float* __restrict__ ow,
                                             const float* __restrict__ ob,
                                             const float* __restrict__ emb,
                                             const float* __restrict__ tfe,
                                             float* __restrict__ yacc,
                                             unsigned short* __restrict__ Tbf,
                                             float* __restrict__ t1,
                                             float* __restrict__ hf,
                                             float* __restrict__ embdot,
                                             float* __restrict__ out,
                                             int E, int N, int NE, int EB)
{
    __shared__ __align__(16) float smem[256*17 + 256];   // 18.4 KB (max role)
    int b = blockIdx.x, t = threadIdx.x;
    if (b < EB) {
        // ---- SH + yacc atomics ----
        float* Yl = smem;                       // [256][17]
        int* sAl = (int*)(smem + 256*17);
        int e = b*256 + t;
        float cx = cell[0], cy = cell[4], cz = cell[8];
        if (e < E) {
            int s = src[e], d = dst[e];
            float x, y, z;
            edge_dir(pos, s, d, cx, cy, cz, x, y, z);
            float o[16];
            sh_eval(x, y, z, o);
            #pragma unroll
            for (int j = 0; j < 16; j++) Yl[t*17 + j] = o[j];
            sAl[t] = s;
        }
        __syncthreads();
        int lastvalid = min(256, E - b*256);
        #pragma unroll
        for (int j = 0; j < 16; j++) {
            int idx = j*256 + t;
            int el = idx >> 4, m = idx & 15;
            if (el < lastvalid)
                atomicAdd(&yacc[(size_t)sAl[el]*16 + m], Yl[el*17 + m]);
        }
    } else if (b < EB + NE) {
        // ---- T-direct: local u1; per-thread direct Gt contraction (no Gt tile) ----
        int a = b - EB;
        float* us = smem;          // [512]
        float* tf = smem + 512;    // [512]
        compute_u1(tw1, vtmp, us, t);
        tf[t]       = tfe[(size_t)a*DF + t];
        tf[t + 256] = tfe[(size_t)a*DF + t + 256];
        __syncthreads();
        int mm = t >> 4, m = t & 15;
        float acc = 0.0f;
        #pragma unroll
        for (int d = 0; d < 32; d++) {
            const float* lrow = lw0 + (size_t)(d*16 + mm)*DF + m;
            float g = 0.0f;
            #pragma unroll
            for (int c = 0; c < 32; c++) g = fmaf(lrow[c*16], us[c*16 + m], g);
            acc = fmaf(tf[d*16 + mm], g, acc);
        }
        Tbf[(size_t)a*256 + mm*16 + m] = f2bf(acc);
        if (t < 16) {
            float s1 = 0.0f;
            #pragma unroll
            for (int d = 0; d < 32; d++) s1 = fmaf(tf[d*16 + t], wv0[d*16 + t], s1);
            t1[(size_t)a*16 + t] = s1;
        }
    } else if (b < EB + 2*NE) {
        // ---- helem: local u1; hf=(emb+lb0).u1 per m; embdot = emb.ow ----
        int a = b - EB - NE;
        float* us = smem;
        float* r2 = smem + 512;
        float* r1 = smem + 1024;
        compute_u1(tw1, vtmp, us, t);
        float e0 = emb[(size_t)a*DF + t];
        float e1 = emb[(size_t)a*DF + t + 256];
        r1[t] = e0*ow[t] + e1*ow[t+256];
        __syncthreads();
        r2[t]       = (e0 + lb0[t])     * us[t];
        r2[t + 256] = (e1 + lb0[t+256]) * us[t+256];
        __syncthreads();
        for (int s = 128; s > 0; s >>= 1) {
            if (t < s) r1[t] += r1[t + s];
            __syncthreads();
        }
        if (t < 16) {
            float s = 0.0f;
            #pragma unroll
            for (int c = 0; c < 32; c++) s += r2[c*16 + t];
            hf[(size_t)a*16 + t] = s;
        }
        if (t == 0) embdot[a] = r1[0];
    } else {
        // ---- constant bias energy: out += N*((lb0+lb1).ow + ob) ----
        float* red = smem;
        red[t] = (lb0[t] + lb1[t])*ow[t] + (lb0[t+256] + lb1[t+256])*ow[t+256];
        __syncthreads();
        for (int s = 128; s > 0; s >>= 1) {
            if (t < s) red[t] += red[t + s];
            __syncthreads();
        }
        if (t == 0) atomicAdd(out, (float)N * (red[0] + ob[0]));
    }
}

// K3: edge-parallel energy; T staged in LDS as bf16 (padded rows), t1 in LDS.
__global__ __launch_bounds__(256) void k_energy(const float* __restrict__ pos,
                                                const int* __restrict__ src,
                                                const int* __restrict__ dst,
                                                const int* __restrict__ an,
                                                const float* __restrict__ cell,
                                                const float* __restrict__ yacc,
                                                const unsigned short* __restrict__ Tbf,
                                                const float* __restrict__ t1,
                                                const float* __restrict__ hf,
                                                const float* __restrict__ embdot,
                                                float* __restrict__ out,
                                                int E, int N, int NE)
{
    __shared__ __align__(16) unsigned short Ts[NEMAX * TPAD];
    __shared__ float t1s[NEMAX * T1PAD];
    __shared__ float wred[4];
    int t = threadIdx.x;
    int nchunk = NE * 32;
    for (int c = t; c < nchunk; c += 256) {
        int a = c >> 5, k = c & 31;
        *(ushort8*)&Ts[a*TPAD + k*8] = *(const ushort8*)&Tbf[(size_t)a*256 + k*8];
    }
    for (int i = t; i < NE*16; i += 256) {
        int a = i >> 4, mm = i & 15;
        t1s[a*T1PAD + mm] = t1[i];
    }
    __syncthreads();

    int i = blockIdx.x * 256 + t;
    float s = 0.0f;
    if (i < E) {
        int sn = src[i], d = dst[i];
        int a = an[sn];
        float x, y, z;
        edge_dir(pos, sn, d, cell[0], cell[4], cell[8], x, y, z);
        float ov[16];
        sh_eval(x, y, z, ov);
        const float4* dp = (const float4*)(yacc + (size_t)d*16);
        float4 D0 = dp[0], D1 = dp[1], D2 = dp[2], D3 = dp[3];
        const unsigned short* Ta = &Ts[a * TPAD];
        const float* ta1 = &t1s[a * T1PAD];
        #pragma unroll
        for (int mm = 0; mm < 16; mm++) {
            ushort8 p0 = *(const ushort8*)&Ta[mm*16];
            ushort8 p1 = *(const ushort8*)&Ta[mm*16 + 8];
            float dotv = bf2f(p0[0])*D0.x + bf2f(p0[1])*D0.y + bf2f(p0[2])*D0.z + bf2f(p0[3])*D0.w
                       + bf2f(p0[4])*D1.x + bf2f(p0[5])*D1.y + bf2f(p0[6])*D1.z + bf2f(p0[7])*D1.w
                       + bf2f(p1[0])*D2.x + bf2f(p1[1])*D2.y + bf2f(p1[2])*D2.z + bf2f(p1[3])*D2.w
                       + bf2f(p1[4])*D3.x + bf2f(p1[5])*D3.y + bf2f(p1[6])*D3.z + bf2f(p1[7])*D3.w;
            s = fmaf(ov[mm], dotv + ta1[mm], s);
        }
    } else if (i < E + N) {
        int n = i - E;
        int a = an[n];
        const float4* hp = (const float4*)(hf + (size_t)a*16);
        float4 H0 = hp[0], H1 = hp[1], H2 = hp[2], H3 = hp[3];
        const float4* vp = (const float4*)(yacc + (size_t)n*16);
        float4 V0 = vp[0], V1 = vp[1], V2 = vp[2], V3 = vp[3];
        s = embdot[a]
          + H0.x*V0.x + H0.y*V0.y + H0.z*V0.z + H0.w*V0.w
          + H1.x*V1.x + H1.y*V1.y + H1.z*V1.z + H1.w*V1.w
          + H2.x*V2.x + H2.y*V2.y + H2.z*V2.z + H2.w*V2.w
          + H3.x*V3.x + H3.y*V3.y + H3.z*V3.z + H3.w*V3.w;
    }
    #pragma unroll
    for (int off = 32; off > 0; off >>= 1) s += __shfl_xor(s, off, 64);
    int lane = t & 63, w = t >> 6;
    if (lane == 0) wred[w] = s;
    __syncthreads();
    if (t == 0) atomicAdd(out, wred[0] + wred[1] + wred[2] + wred[3]);
}

extern "C" void kernel_launch(void* const* d_in, const int* in_sizes, int n_in,
                              void* d_out, int out_size, void* d_ws, size_t ws_size,
                              hipStream_t stream)
{
    const float* pos  = (const float*)d_in[0];
    const float* cell = (const float*)d_in[1];
    const int*   an   = (const int*)d_in[2];
    const int*   ei   = (const int*)d_in[3];
    const float* emb  = (const float*)d_in[4];
    const float* tw0  = (const float*)d_in[5];
    const float* lw0  = (const float*)d_in[6];
    const float* lb0  = (const float*)d_in[7];
    const float* tw1  = (const float*)d_in[8];
    const float* lw1  = (const float*)d_in[9];
    const float* lb1  = (const float*)d_in[10];
    const float* ow   = (const float*)d_in[11];
    const float* ob   = (const float*)d_in[12];
    int N  = in_sizes[0] / 3;
    int E  = in_sizes[3] / 2;
    int NE = in_sizes[4] / DF;   // 89 elements
    const int* src = ei;
    const int* dst = ei + E;

    char* ws = (char*)d_ws;
    size_t off = 0;
    auto alloc = [&](size_t bytes) { void* p = ws + off; off += (bytes + 255) / 256 * 256; return p; };

    float* tfe    = (float*)alloc((size_t)NE * DF * 4);
    float* vtmp   = (float*)alloc(DF * 4);
    float* wv0    = (float*)alloc(DF * 4);
    unsigned short* Tbf = (unsigned short*)alloc((size_t)NE * 256 * 2);
    float* t1     = (float*)alloc((size_t)NE * 16 * 4);
    float* hf     = (float*)alloc((size_t)NE * 16 * 4);
    float* embdot = (float*)alloc((size_t)NE * 4);
    float* yacc   = (float*)alloc((size_t)N * 16 * 4);

    float* out = (float*)d_out;

    int nyacc4 = N * 4;
    int zblocks = (nyacc4 + 511) / 512;
    k_setup<<<128 + NE + zblocks, 512, 0, stream>>>(
        lw1, lw0, ow, emb, tw0, vtmp, wv0, tfe, (uint4*)yacc, nyacc4, out, NE);

    int EB = (E + 255) / 256;
    k_mid<<<EB + 2*NE + 1, 256, 0, stream>>>(
        pos, src, dst, cell, vtmp, wv0, tw1, lw0, lb0, lb1, ow, ob, emb, tfe,
        yacc, Tbf, t1, hf, embdot, out, E, N, NE, EB);

    k_energy<<<(E + N + 255) / 256, 256, 0, stream>>>(
        pos, src, dst, an, cell, yacc, Tbf, t1, hf, embdot, out, E, N, NE);
}

// Round 16
// 52.660 us; speedup vs baseline: 1.5392x; 1.1788x over previous
//
#include <hip/hip_runtime.h>
#include <math.h>

#define DF 512
#define NEMAX 89
#define TPAD 264   // ushorts per padded T row in k_energy LDS
#define T1PAD 17

typedef __attribute__((ext_vector_type(8))) unsigned short ushort8;

__device__ __constant__ int c_lidx[16] = {0,1,1,1,2,2,2,2,2,3,3,3,3,3,3,3};

__device__ inline float bf2f(unsigned short s) {
    union { unsigned int u; float f; } x;
    x.u = ((unsigned int)s) << 16;
    return x.f;
}
__device__ inline unsigned short f2bf(float f) {
    union { float f; unsigned int u; } x; x.f = f;
    unsigned int r = x.u + 0x7fffu + ((x.u >> 16) & 1u);
    return (unsigned short)(r >> 16);
}

__device__ inline void sh_eval(float x, float y, float z, float* o)
{
    float x2 = x*x, y2 = y*y, z2 = z*z;
    o[0]  = 0.28209479177387814f;
    o[1]  = 0.4886025119029199f*y;
    o[2]  = 0.4886025119029199f*z;
    o[3]  = 0.4886025119029199f*x;
    o[4]  = 1.0925484305920792f*x*y;
    o[5]  = 1.0925484305920792f*y*z;
    o[6]  = 0.31539156525252005f*(3.0f*z2 - 1.0f);
    o[7]  = 1.0925484305920792f*x*z;
    o[8]  = 0.5462742152960396f*(x2 - y2);
    o[9]  = 0.5900435899266435f*y*(3.0f*x2 - y2);
    o[10] = 2.890611442640554f*x*y*z;
    o[11] = 0.4570457994644658f*y*(5.0f*z2 - 1.0f);
    o[12] = 0.3731763325901154f*z*(5.0f*z2 - 3.0f);
    o[13] = 0.4570457994644658f*x*(5.0f*z2 - 1.0f);
    o[14] = 1.445305721320277f*z*(x2 - y2);
    o[15] = 0.5900435899266435f*x*(x2 - 3.0f*y2);
}

__device__ inline void edge_dir(const float* __restrict__ pos, int s, int d,
                                float cx, float cy, float cz,
                                float& x, float& y, float& z)
{
    float ex = pos[d*3+0] - pos[s*3+0];
    float ey = pos[d*3+1] - pos[s*3+1];
    float ez = pos[d*3+2] - pos[s*3+2];
    ex -= rintf(ex/cx)*cx;
    ey -= rintf(ey/cy)*cy;
    ez -= rintf(ez/cz)*cz;
    float len = fmaxf(sqrtf(ex*ex + ey*ey + ez*ez), 1e-8f);
    x = ex/len; y = ey/len; z = ez/len;
}

// us[c*16+m] = sum_d tw1[l(m)][c][d] * v[d*16+m]   (256 threads, 2 outputs each)
__device__ inline void compute_u1(const float* __restrict__ tw1,
                                  const float* __restrict__ v,
                                  float* __restrict__ us, int t)
{
    #pragma unroll
    for (int rep = 0; rep < 2; rep++) {
        int f = t + rep*256;
        int c = f >> 4, m = f & 15, l = c_lidx[m];
        float u = 0.0f;
        #pragma unroll
        for (int d = 0; d < 32; d++) u = fmaf(tw1[l*1024 + c*32 + d], v[d*16 + m], u);
        us[f] = u;
    }
}

// K1: [0,64) vtmp=lw1@ow; [64,128) wv0=lw0@ow; [128,128+NE) tfe; rest: zero yacc + out
__global__ __launch_bounds__(512) void k_setup(const float* __restrict__ lw1,
                                               const float* __restrict__ lw0,
                                               const float* __restrict__ ow,
                                               const float* __restrict__ emb,
                                               const float* __restrict__ tw0,
                                               float* __restrict__ vtmp,
                                               float* __restrict__ wv0,
                                               float* __restrict__ tfe,
                                               uint4* __restrict__ yacc4, int nyacc4,
                                               float* __restrict__ out, int NE)
{
    int b = blockIdx.x, t = threadIdx.x;
    if (b < 128) {
        const float* w = (b < 64) ? lw1 : lw0;
        float* v = (b < 64) ? vtmp : wv0;
        int bb = b & 63;
        int r = bb*8 + (t >> 6);
        int lane = t & 63;
        const float* row = w + (size_t)r * DF;
        float s = 0.0f;
        #pragma unroll
        for (int j = 0; j < 8; j++) s += row[lane + j*64] * ow[lane + j*64];
        #pragma unroll
        for (int off = 32; off > 0; off >>= 1) s += __shfl_xor(s, off, 64);
        if (lane == 0) v[r] = s;
    } else if (b < 128 + NE) {
        __shared__ float nf[DF];
        __shared__ float w[4*32*32];
        int a = b - 128;
        nf[t] = emb[(size_t)a*DF + t];
        for (int i = t; i < 4096; i += 512) w[i] = tw0[i];
        __syncthreads();
        int d = t >> 4, m = t & 15;
        int l = c_lidx[m];
        const float* wl = &w[l*1024 + d];
        float acc = 0.0f;
        #pragma unroll
        for (int c = 0; c < 32; c++) acc += nf[c*16 + m] * wl[c*32];
        tfe[(size_t)a*DF + t] = acc;
    } else {
        int i = (b - 128 - NE)*512 + t;
        if (i < nyacc4) yacc4[i] = make_uint4(0,0,0,0);
        if (i == 0) out[0] = 0.0f;
    }
}

// K2 "mid" (18.4 KB LDS, all roles): [0,EB) sh+yacc atomics; [EB,EB+NE) T-direct;
// [EB+NE,EB+2NE) helem; [EB+2NE] bias
__global__ __launch_bounds__(256) void k_mid(const float* __restrict__ pos,
                                             const int* __restrict__ src,
                                             const int* __restrict__ dst,
                                             const float* __restrict__ cell,
                                             const float* __restrict__ vtmp,
                                             const float* __restrict__ wv0,
                                             const float* __restrict__ tw1,
                                             const float* __restrict__ lw0,
                                             const float* __restrict__ lb0,
                                             const float* __restrict__ lb1,
                                             const float* __restrict__ ow,
                                             const float* __restrict__ ob,
                                             const float* __restrict__ emb,
                                             const float* __restrict__ tfe,
                                             float* __restrict__ yacc,
                                             unsigned short* __restrict__ Tbf,
                                             float* __restrict__ t1,
                                             float* __restrict__ hf,
                                             float* __restrict__ embdot,
                                             float* __restrict__ out,
                                             int E, int N, int NE, int EB)
{
    __shared__ __align__(16) float smem[256*17 + 256];   // 18.4 KB (max role)
    int b = blockIdx.x, t = threadIdx.x;
    if (b < EB) {
        // ---- SH + yacc atomics ----
        float* Yl = smem;                       // [256][17]
        int* sAl = (int*)(smem + 256*17);
        int e = b*256 + t;
        float cx = cell[0], cy = cell[4], cz = cell[8];
        if (e < E) {
            int s = src[e], d = dst[e];
            float x, y, z;
            edge_dir(pos, s, d, cx, cy, cz, x, y, z);
            float o[16];
            sh_eval(x, y, z, o);
            #pragma unroll
            for (int j = 0; j < 16; j++) Yl[t*17 + j] = o[j];
            sAl[t] = s;
        }
        __syncthreads();
        int lastvalid = min(256, E - b*256);
        #pragma unroll
        for (int j = 0; j < 16; j++) {
            int idx = j*256 + t;
            int el = idx >> 4, m = idx & 15;
            if (el < lastvalid)
                atomicAdd(&yacc[(size_t)sAl[el]*16 + m], Yl[el*17 + m]);
        }
    } else if (b < EB + NE) {
        // ---- T-direct: local u1; per-thread direct Gt contraction (no Gt tile) ----
        int a = b - EB;
        float* us = smem;          // [512]
        float* tf = smem + 512;    // [512]
        compute_u1(tw1, vtmp, us, t);
        tf[t]       = tfe[(size_t)a*DF + t];
        tf[t + 256] = tfe[(size_t)a*DF + t + 256];
        __syncthreads();
        int mm = t >> 4, m = t & 15;
        float acc = 0.0f;
        #pragma unroll
        for (int d = 0; d < 32; d++) {
            const float* lrow = lw0 + (size_t)(d*16 + mm)*DF + m;
            float g = 0.0f;
            #pragma unroll
            for (int c = 0; c < 32; c++) g = fmaf(lrow[c*16], us[c*16 + m], g);
            acc = fmaf(tf[d*16 + mm], g, acc);
        }
        Tbf[(size_t)a*256 + mm*16 + m] = f2bf(acc);
        if (t < 16) {
            float s1 = 0.0f;
            #pragma unroll
            for (int d = 0; d < 32; d++) s1 = fmaf(tf[d*16 + t], wv0[d*16 + t], s1);
            t1[(size_t)a*16 + t] = s1;
        }
    } else if (b < EB + 2*NE) {
        // ---- helem: local u1; hf=(emb+lb0).u1 per m; embdot = emb.ow ----
        int a = b - EB - NE;
        float* us = smem;
        float* r2 = smem + 512;
        float* r1 = smem + 1024;
        compute_u1(tw1, vtmp, us, t);
        float e0 = emb[(size_t)a*DF + t];
        float e1 = emb[(size_t)a*DF + t + 256];
        r1[t] = e0*ow[t] + e1*ow[t+256];
        __syncthreads();
        r2[t]       = (e0 + lb0[t])     * us[t];
        r2[t + 256] = (e1 + lb0[t+256]) * us[t+256];
        __syncthreads();
        for (int s = 128; s > 0; s >>= 1) {
            if (t < s) r1[t] += r1[t + s];
            __syncthreads();
        }
        if (t < 16) {
            float s = 0.0f;
            #pragma unroll
            for (int c = 0; c < 32; c++) s += r2[c*16 + t];
            hf[(size_t)a*16 + t] = s;
        }
        if (t == 0) embdot[a] = r1[0];
    } else {
        // ---- constant bias energy: out += N*((lb0+lb1).ow + ob) ----
        float* red = smem;
        red[t] = (lb0[t] + lb1[t])*ow[t] + (lb0[t+256] + lb1[t+256])*ow[t+256];
        __syncthreads();
        for (int s = 128; s > 0; s >>= 1) {
            if (t < s) red[t] += red[t + s];
            __syncthreads();
        }
        if (t == 0) atomicAdd(out, (float)N * (red[0] + ob[0]));
    }
}

// K3: edge-parallel energy; 1024 threads/block for full occupancy (LDS 53 KB,
// 2 blocks/CU by the 32-wave cap -> 32 waves/CU vs 12 at 256-thread blocks).
__global__ __launch_bounds__(1024) void k_energy(const float* __restrict__ pos,
                                                 const int* __restrict__ src,
                                                 const int* __restrict__ dst,
                                                 const int* __restrict__ an,
                                                 const float* __restrict__ cell,
                                                 const float* __restrict__ yacc,
                                                 const unsigned short* __restrict__ Tbf,
                                                 const float* __restrict__ t1,
                                                 const float* __restrict__ hf,
                                                 const float* __restrict__ embdot,
                                                 float* __restrict__ out,
                                                 int E, int N, int NE)
{
    __shared__ __align__(16) unsigned short Ts[NEMAX * TPAD];
    __shared__ float t1s[NEMAX * T1PAD];
    __shared__ float wred[16];
    int t = threadIdx.x;
    int nchunk = NE * 32;
    for (int c = t; c < nchunk; c += 1024) {
        int a = c >> 5, k = c & 31;
        *(ushort8*)&Ts[a*TPAD + k*8] = *(const ushort8*)&Tbf[(size_t)a*256 + k*8];
    }
    for (int i = t; i < NE*16; i += 1024) {
        int a = i >> 4, mm = i & 15;
        t1s[a*T1PAD + mm] = t1[i];
    }
    __syncthreads();

    int i = blockIdx.x * 1024 + t;
    float s = 0.0f;
    if (i < E) {
        int sn = src[i], d = dst[i];
        int a = an[sn];
        float x, y, z;
        edge_dir(pos, sn, d, cell[0], cell[4], cell[8], x, y, z);
        float ov[16];
        sh_eval(x, y, z, ov);
        const float4* dp = (const float4*)(yacc + (size_t)d*16);
        float4 D0 = dp[0], D1 = dp[1], D2 = dp[2], D3 = dp[3];
        const unsigned short* Ta = &Ts[a * TPAD];
        const float* ta1 = &t1s[a * T1PAD];
        #pragma unroll
        for (int mm = 0; mm < 16; mm++) {
            ushort8 p0 = *(const ushort8*)&Ta[mm*16];
            ushort8 p1 = *(const ushort8*)&Ta[mm*16 + 8];
            float dotv = bf2f(p0[0])*D0.x + bf2f(p0[1])*D0.y + bf2f(p0[2])*D0.z + bf2f(p0[3])*D0.w
                       + bf2f(p0[4])*D1.x + bf2f(p0[5])*D1.y + bf2f(p0[6])*D1.z + bf2f(p0[7])*D1.w
                       + bf2f(p1[0])*D2.x + bf2f(p1[1])*D2.y + bf2f(p1[2])*D2.z + bf2f(p1[3])*D2.w
                       + bf2f(p1[4])*D3.x + bf2f(p1[5])*D3.y + bf2f(p1[6])*D3.z + bf2f(p1[7])*D3.w;
            s = fmaf(ov[mm], dotv + ta1[mm], s);
        }
    } else if (i < E + N) {
        int n = i - E;
        int a = an[n];
        const float4* hp = (const float4*)(hf + (size_t)a*16);
        float4 H0 = hp[0], H1 = hp[1], H2 = hp[2], H3 = hp[3];
        const float4* vp = (const float4*)(yacc + (size_t)n*16);
        float4 V0 = vp[0], V1 = vp[1], V2 = vp[2], V3 = vp[3];
        s = embdot[a]
          + H0.x*V0.x + H0.y*V0.y + H0.z*V0.z + H0.w*V0.w
          + H1.x*V1.x + H1.y*V1.y + H1.z*V1.z + H1.w*V1.w
          + H2.x*V2.x + H2.y*V2.y + H2.z*V2.z + H2.w*V2.w
          + H3.x*V3.x + H3.y*V3.y + H3.z*V3.z + H3.w*V3.w;
    }
    #pragma unroll
    for (int off = 32; off > 0; off >>= 1) s += __shfl_xor(s, off, 64);
    int lane = t & 63, w = t >> 6;
    if (lane == 0) wred[w] = s;
    __syncthreads();
    if (t == 0) {
        float tot = 0.0f;
        #pragma unroll
        for (int j = 0; j < 16; j++) tot += wred[j];
        atomicAdd(out, tot);
    }
}

extern "C" void kernel_launch(void* const* d_in, const int* in_sizes, int n_in,
                              void* d_out, int out_size, void* d_ws, size_t ws_size,
                              hipStream_t stream)
{
    const float* pos  = (const float*)d_in[0];
    const float* cell = (const float*)d_in[1];
    const int*   an   = (const int*)d_in[2];
    const int*   ei   = (const int*)d_in[3];
    const float* emb  = (const float*)d_in[4];
    const float* tw0  = (const float*)d_in[5];
    const float* lw0  = (const float*)d_in[6];
    const float* lb0  = (const float*)d_in[7];
    const float* tw1  = (const float*)d_in[8];
    const float* lw1  = (const float*)d_in[9];
    const float* lb1  = (const float*)d_in[10];
    const float* ow   = (const float*)d_in[11];
    const float* ob   = (const float*)d_in[12];
    int N  = in_sizes[0] / 3;
    int E  = in_sizes[3] / 2;
    int NE = in_sizes[4] / DF;   // 89 elements
    const int* src = ei;
    const int* dst = ei + E;

    char* ws = (char*)d_ws;
    size_t off = 0;
    auto alloc = [&](size_t bytes) { void* p = ws + off; off += (bytes + 255) / 256 * 256; return p; };

    float* tfe    = (float*)alloc((size_t)NE * DF * 4);
    float* vtmp   = (float*)alloc(DF * 4);
    float* wv0    = (float*)alloc(DF * 4);
    unsigned short* Tbf = (unsigned short*)alloc((size_t)NE * 256 * 2);
    float* t1     = (float*)alloc((size_t)NE * 16 * 4);
    float* hf     = (float*)alloc((size_t)NE * 16 * 4);
    float* embdot = (float*)alloc((size_t)NE * 4);
    float* yacc   = (float*)alloc((size_t)N * 16 * 4);

    float* out = (float*)d_out;

    int nyacc4 = N * 4;
    int zblocks = (nyacc4 + 511) / 512;
    k_setup<<<128 + NE + zblocks, 512, 0, stream>>>(
        lw1, lw0, ow, emb, tw0, vtmp, wv0, tfe, (uint4*)yacc, nyacc4, out, NE);

    int EB = (E + 255) / 256;
    k_mid<<<EB + 2*NE + 1, 256, 0, stream>>>(
        pos, src, dst, cell, vtmp, wv0, tw1, lw0, lb0, lb1, ow, ob, emb, tfe,
        yacc, Tbf, t1, hf, embdot, out, E, N, NE, EB);

    k_energy<<<(E + N + 1023) / 1024, 1024, 0, stream>>>(
        pos, src, dst, an, cell, yacc, Tbf, t1, hf, embdot, out, E, N, NE);
}